// Round 23
// baseline (187.741 us; speedup 1.0000x reference)
//
#include <hip/hip_runtime.h>
#include <math.h>

#define N_NODES_C 50000
#define N_EDGES_C 200000
#define FDIM 128
#define NRBF 20
#define CUT 5.0f
#define SC_BLK 196   // ceil(50000/256)
#define GBLOCKS 6250 // 8 nodes per block
#define BATCH 32     // edges staged per LDS batch (32 x 64B = 2KB = 128 float4)

// K1 partition: [vpack 4096 | count 782 | prep_all 272]
#define K1_VP 4096
#define K1_CT 782
#define K1_PR 272
// K5 partition: [mlp1w 782 | fill 782]
#define K5_ML 782
#define K5_FL 782

typedef short  bf16x8 __attribute__((ext_vector_type(8)));
typedef float  f32x4  __attribute__((ext_vector_type(4)));
typedef unsigned int u32x3 __attribute__((ext_vector_type(3)));
typedef _Float16 f16x2 __attribute__((ext_vector_type(2)));

__device__ __forceinline__ unsigned short f32_to_bf16(float f) {
    unsigned u = __float_as_uint(f);
    unsigned r = (u + 0x7FFFu + ((u >> 16) & 1u)) >> 16;   // RNE
    return (unsigned short)r;
}
__device__ __forceinline__ float bf16_to_f32(unsigned short h) {
    return __uint_as_float(((unsigned)h) << 16);
}
__device__ __forceinline__ unsigned short f16_bits(float x) {
    _Float16 h = (_Float16)x;
    unsigned short b;
    __builtin_memcpy(&b, &h, 2);
    return b;
}
__device__ __forceinline__ f16x2 u2h2(unsigned u) {
    f16x2 r;
    __builtin_memcpy(&r, &u, 4);
    return r;
}
__device__ __forceinline__ bf16x8 pack_bf16x8(f32x4 a, f32x4 b) {
    bf16x8 r;
    r[0] = (short)f32_to_bf16(a[0]); r[1] = (short)f32_to_bf16(a[1]);
    r[2] = (short)f32_to_bf16(a[2]); r[3] = (short)f32_to_bf16(a[3]);
    r[4] = (short)f32_to_bf16(b[0]); r[5] = (short)f32_to_bf16(b[1]);
    r[6] = (short)f32_to_bf16(b[2]); r[7] = (short)f32_to_bf16(b[3]);
    return r;
}

// ---------------------------------------------------------------------------
// K1: merged [vpack | count | prep_all] — independent work, block-partitioned.
// ---------------------------------------------------------------------------
__global__ __launch_bounds__(256) void k1_kernel(
    const float* __restrict__ v, unsigned short* __restrict__ pv,
    const int* __restrict__ dst, int* __restrict__ counts,
    const float* __restrict__ W1, const float* __restrict__ W2,
    const float* __restrict__ Wr, unsigned short* __restrict__ W1t,
    unsigned short* __restrict__ W2t, unsigned* __restrict__ wrh)
{
    const int bid = blockIdx.x;
    const int tid = threadIdx.x;

    if (bid < K1_VP) {
        const int total = N_NODES_C * 128;
        for (int idx = bid * 256 + tid; idx < total; idx += K1_VP * 256) {
            int n = idx >> 7, f = idx & 127;
            const float* vr = v + (size_t)n * 384;
            unsigned short v0 = f32_to_bf16(__builtin_nontemporal_load(vr + f));
            unsigned short v1 = f32_to_bf16(__builtin_nontemporal_load(vr + 128 + f));
            unsigned short v2 = f32_to_bf16(__builtin_nontemporal_load(vr + 256 + f));
            char* base = (char*)pv + (size_t)n * 1536 + (size_t)f * 12;
            *(unsigned short*)(base + 6) = v0;
            *(unsigned*)(base + 8) = (unsigned)v1 | ((unsigned)v2 << 16);
        }
    } else if (bid < K1_VP + K1_CT) {
        int e = (bid - K1_VP) * 256 + tid;
        if (e < N_EDGES_C) atomicAdd(counts + dst[e], 1);
    } else {
        int i = (bid - K1_VP - K1_CT) * 256 + tid;
        if (i < 128 * 128) {
            int n = i >> 7, k = i & 127;
            W1t[i] = f32_to_bf16(W1[k * 128 + n]);
        } else if (i < 128 * 128 + 384 * 128) {
            int j = i - 128 * 128;
            int n = j >> 7, k = j & 127;
            W2t[j] = f32_to_bf16(W2[k * 384 + n]);
        } else {
            int idx = i - (128 * 128 + 384 * 128);
            if (idx < 128 * 30) {
                int f  = idx / 30;
                int r  = idx % 30;
                int sec = r / 10, kp = r % 10;
                int col = sec * 128 + f;
                unsigned lo = f16_bits(Wr[(2 * kp)     * 384 + col]);
                unsigned hi = f16_bits(Wr[(2 * kp + 1) * 384 + col]);
                wrh[idx] = lo | (hi << 16);
            }
        }
    }
}

// ---------------------------------------------------------------------------
// CSR scan: 3-kernel parallel scan
// ---------------------------------------------------------------------------
__global__ __launch_bounds__(256) void scan1_kernel(
    const int* __restrict__ counts, int* __restrict__ row_tmp,
    int* __restrict__ partial)
{
    __shared__ int sm[256];
    const int t = threadIdx.x;
    const int idx = blockIdx.x * 256 + t;
    int c = (idx < N_NODES_C) ? counts[idx] : 0;
    int x = c;
    sm[t] = x;
    __syncthreads();
#pragma unroll
    for (int off = 1; off < 256; off <<= 1) {
        int y = (t >= off) ? sm[t - off] : 0;
        __syncthreads();
        x += y;
        sm[t] = x;
        __syncthreads();
    }
    if (idx < N_NODES_C) row_tmp[idx] = x - c;
    if (t == 255) partial[blockIdx.x] = x;
}

__global__ __launch_bounds__(256) void scan2_kernel(
    const int* __restrict__ partial, int* __restrict__ poffs)
{
    __shared__ int sm[256];
    const int t = threadIdx.x;
    int c = (t < SC_BLK) ? partial[t] : 0;
    int x = c;
    sm[t] = x;
    __syncthreads();
#pragma unroll
    for (int off = 1; off < 256; off <<= 1) {
        int y = (t >= off) ? sm[t - off] : 0;
        __syncthreads();
        x += y;
        sm[t] = x;
        __syncthreads();
    }
    if (t < SC_BLK) poffs[t] = x - c;
}

__global__ __launch_bounds__(256) void scan3_kernel(
    const int* __restrict__ row_tmp, const int* __restrict__ poffs,
    int* __restrict__ row_ptr, int* __restrict__ row_fill)
{
    const int idx = blockIdx.x * 256 + threadIdx.x;
    if (idx < N_NODES_C) {
        int rp = row_tmp[idx] + poffs[blockIdx.x];
        row_ptr[idx]  = rp;
        row_fill[idx] = rp;
    }
    if (idx == 0) row_ptr[N_NODES_C] = N_EDGES_C;
}

// ---------------------------------------------------------------------------
// K5: merged [mlp1w | fill]
// ---------------------------------------------------------------------------
__global__ __launch_bounds__(256) void k5_kernel(
    const float* __restrict__ s, const unsigned short* __restrict__ W1t,
    const float* __restrict__ b1, unsigned short* __restrict__ h,
    const float* __restrict__ rel_pos, const int* __restrict__ src,
    const int* __restrict__ dst, int* __restrict__ row_fill,
    float* __restrict__ e_meta)
{
    __shared__ unsigned short w1lds[128 * 136];   // 34.8 KB (mlp1w branch)

    const int bid = blockIdx.x;
    const int tid = threadIdx.x;

    if (bid < K5_ML) {
#pragma unroll
        for (int j = 0; j < 8; ++j) {
            int fi = tid + j * 256;
            int row  = fi >> 4;
            int colq = fi & 15;
            *(float4*)&w1lds[row * 136 + colq * 8] =
                *(const float4*)(W1t + (size_t)fi * 8);
        }
        __syncthreads();

        const int wv = tid >> 6, lane = tid & 63;
        const int m0 = bid * 64 + wv * 16;
        const int lr = lane & 15, lg = lane >> 4;
        int arow = m0 + lr; if (arow >= N_NODES_C) arow = N_NODES_C - 1;

        f32x4 acc[8];
#pragma unroll
        for (int nt = 0; nt < 8; ++nt) acc[nt] = (f32x4){0.f, 0.f, 0.f, 0.f};

#pragma unroll
        for (int kt = 0; kt < 4; ++kt) {
            const int k0 = kt * 32 + lg * 8;
            const f32x4* ap = (const f32x4*)(s + (size_t)arow * 128 + k0);
            f32x4 a0 = __builtin_nontemporal_load(ap);
            f32x4 a1 = __builtin_nontemporal_load(ap + 1);
            bf16x8 af = pack_bf16x8(a0, a1);
#pragma unroll
            for (int nt = 0; nt < 8; ++nt) {
                bf16x8 bf = *(const bf16x8*)&w1lds[(nt * 16 + lr) * 136 + k0];
                acc[nt] = __builtin_amdgcn_mfma_f32_16x16x32_bf16(af, bf, acc[nt], 0, 0, 0);
            }
        }

        const int crow = m0 + lg * 4;
#pragma unroll
        for (int nt = 0; nt < 8; ++nt) {
            int col = nt * 16 + lr;
            float bb = b1[col];
#pragma unroll
            for (int r = 0; r < 4; ++r) {
                int m = crow + r;
                if (m < N_NODES_C) {
                    float x = acc[nt][r] + bb;
                    x = x / (1.f + __expf(-x));
                    h[(size_t)m * 128 + col] = f32_to_bf16(x);
                }
            }
        }
    } else {
        int e = (bid - K5_ML) * 256 + tid;
        if (e >= N_EDGES_C) return;

        int pos = atomicAdd(row_fill + dst[e], 1);

        float x = rel_pos[3 * e + 0];
        float y = rel_pos[3 * e + 1];
        float z = rel_pos[3 * e + 2];
        float d = sqrtf(x * x + y * y + z * z);
        float invd = 1.0f / d;

        float s1 = 0.f, c1 = 0.f, fcut = 0.f, amp = 0.f;
        if (d < CUT) {
            sincosf((3.14159265358979f / CUT) * d, &s1, &c1);
            fcut = 0.5f * (c1 + 1.0f);
            amp  = invd * fcut;
        }

        float rb[NRBF];
        float sk = s1, ck = c1;
#pragma unroll
        for (int k = 0; k < NRBF; ++k) {
            rb[k] = sk * amp;
            float sn = sk * c1 + ck * s1;
            ck = ck * c1 - sk * s1;
            sk = sn;
        }

        unsigned pk[10];
#pragma unroll
        for (int kp = 0; kp < 10; ++kp)
            pk[kp] = (unsigned)f16_bits(rb[2 * kp]) | ((unsigned)f16_bits(rb[2 * kp + 1]) << 16);

        float4* mp = (float4*)(e_meta + (size_t)pos * 16);
        mp[0] = make_float4(x * invd, y * invd, z * invd, fcut);
        mp[1] = make_float4(__uint_as_float(pk[0]), __uint_as_float(pk[1]),
                            __uint_as_float(pk[2]), __uint_as_float(pk[3]));
        mp[2] = make_float4(__uint_as_float(pk[4]), __uint_as_float(pk[5]),
                            __uint_as_float(pk[6]), __uint_as_float(pk[7]));
        mp[3] = make_float4(__uint_as_float(pk[8]), __uint_as_float(pk[9]),
                            __int_as_float(src[e]), 0.f);
    }
}

// ---------------------------------------------------------------------------
// MLP stage 2 -> p-half of pv. ROUND-23 RESTRUCTURE: grid (391, 4) with
// blockIdx.y = t; each block stages its W2t slice pair ONCE (1 barrier),
// then loops 4 row-tiles barrier-free. Round-22 analysis: per-block
// re-staging cost 1563 x 4 x 24.6KB = 154MB of W2t traffic (data is 98KB)
// plus 8 barrier stalls/block — this cuts staging to 38MB and 1 barrier.
// ---------------------------------------------------------------------------
__global__ __launch_bounds__(256) void mlp2p_kernel(
    const unsigned short* __restrict__ h, const unsigned short* __restrict__ W2t,
    const float* __restrict__ b2, unsigned short* __restrict__ pv)
{
    __shared__ unsigned short wlds[2][3 * 16 * 136];   // [half] 26.1 KB

    const int tid = threadIdx.x;
    const int t  = blockIdx.y;        // 0..3 nt-step
    const int wv = tid >> 6, lane = tid & 63;
    const int rg = wv & 1;            // row-group
    const int hf = wv >> 1;           // nt-half
    const int lr = lane & 15, lg = lane >> 4;

    // stage both halves' slices for this t: 1536 float4 over 256 threads
#pragma unroll
    for (int j = 0; j < 6; ++j) {
        int fi = tid + j * 256;            // 0..1535
        int half = (fi >= 768) ? 1 : 0;
        int rem  = fi - half * 768;
        int c    = rem >> 8;               // 0..2
        int r2   = rem & 255;
        int row  = r2 >> 4;
        int colq = r2 & 15;
        int nt   = half * 4 + t;
        *(float4*)&wlds[half][(c * 16 + row) * 136 + colq * 8] =
            *(const float4*)(W2t +
                ((size_t)(c * 128 + nt * 16 + row) * 128 + colq * 8));
    }
    __syncthreads();

    const unsigned short* W = wlds[hf];
    const int col = (hf * 4 + t) * 16 + lr;
    const float bb0 = b2[col], bb1 = b2[128 + col], bb2 = b2[256 + col];

    // loop 4 row-tiles of 32 rows (block covers 128 rows), barrier-free
    for (int sub = 0; sub < 4; ++sub) {
        const int m0 = blockIdx.x * 128 + sub * 32 + rg * 16;
        if (m0 >= N_NODES_C) break;
        int arow = m0 + lr; if (arow >= N_NODES_C) arow = N_NODES_C - 1;

        bf16x8 af2[4];
#pragma unroll
        for (int kt = 0; kt < 4; ++kt)
            af2[kt] = *(const bf16x8*)(h + (size_t)arow * 128 + kt * 32 + lg * 8);

        f32x4 a0 = (f32x4){0.f, 0.f, 0.f, 0.f};
        f32x4 a1 = (f32x4){0.f, 0.f, 0.f, 0.f};
        f32x4 a2 = (f32x4){0.f, 0.f, 0.f, 0.f};
#pragma unroll
        for (int kt = 0; kt < 4; ++kt) {
            const int k0 = kt * 32 + lg * 8;
            bf16x8 bf0 = *(const bf16x8*)&W[(      lr) * 136 + k0];
            bf16x8 bf1 = *(const bf16x8*)&W[(16 +  lr) * 136 + k0];
            bf16x8 bf2 = *(const bf16x8*)&W[(32 +  lr) * 136 + k0];
            a0 = __builtin_amdgcn_mfma_f32_16x16x32_bf16(af2[kt], bf0, a0, 0, 0, 0);
            a1 = __builtin_amdgcn_mfma_f32_16x16x32_bf16(af2[kt], bf1, a1, 0, 0, 0);
            a2 = __builtin_amdgcn_mfma_f32_16x16x32_bf16(af2[kt], bf2, a2, 0, 0, 0);
        }

        const int crow = m0 + lg * 4;
#pragma unroll
        for (int r = 0; r < 4; ++r) {
            int m = crow + r;
            if (m < N_NODES_C) {
                unsigned p0 = f32_to_bf16(a0[r] + bb0);
                unsigned p1 = f32_to_bf16(a1[r] + bb1);
                unsigned short p2 = f32_to_bf16(a2[r] + bb2);
                char* base = (char*)pv + (size_t)m * 1536 + (size_t)col * 12;
                *(unsigned*)(base) = p0 | (p1 << 16);
                *(unsigned short*)(base + 4) = p2;
            }
        }
    }
}

// ---------------------------------------------------------------------------
// Gather: round-15 structure (measured best). nt meta loads + nt output
// stores. Single 12B pv record per edge, f16-dot2, asm-pin Wr loads.
// ---------------------------------------------------------------------------
#define COMPUTE_E(M_, U)                                                       \
    {                                                                          \
        const float4 m0 = *(const float4*)(M_);                                \
        const unsigned* mu_ = (const unsigned*)((M_) + 4);                     \
        float w0 = m0.w * br0, w1 = m0.w * br1, w2 = m0.w * br2;               \
        _Pragma("unroll")                                                      \
        for (int kp = 0; kp < 10; ++kp) {                                      \
            f16x2 rh = u2h2(mu_[kp]);                                          \
            w0 = __builtin_amdgcn_fdot2(rh, u2h2(wrp0[kp]), w0, false);        \
            w1 = __builtin_amdgcn_fdot2(rh, u2h2(wrp1[kp]), w1, false);        \
            w2 = __builtin_amdgcn_fdot2(rh, u2h2(wrp2[kp]), w2, false);        \
        }                                                                      \
        float P0 = bf16_to_f32((unsigned short)((U).x & 0xFFFFu));             \
        float P1 = bf16_to_f32((unsigned short)((U).x >> 16));                 \
        float P2 = bf16_to_f32((unsigned short)((U).y & 0xFFFFu));             \
        float V0 = bf16_to_f32((unsigned short)((U).y >> 16));                 \
        float V1 = bf16_to_f32((unsigned short)((U).z & 0xFFFFu));             \
        float V2 = bf16_to_f32((unsigned short)((U).z >> 16));                 \
        float sv = w0 * P0;                                                    \
        float ss = w1 * P1;                                                    \
        float sr = w2 * P2;                                                    \
        acc_s  += ss;                                                          \
        acc_v0 += V0 * sv + m0.x * sr;                                         \
        acc_v1 += V1 * sv + m0.y * sr;                                         \
        acc_v2 += V2 * sv + m0.z * sr;                                         \
    }

#define LOADPV(U, SI)                                                          \
    U = *(const u32x3*)((const char*)pv + (size_t)(SI) * 1536 + (size_t)f * 12);

#define STORE_NODE(N_, AS, A0, A1, A2)                                         \
    {                                                                          \
        __builtin_nontemporal_store(AS, &out_s[(size_t)(N_) * 128 + f]);       \
        __builtin_nontemporal_store(A0, &out_v[(size_t)(N_) * 384 +       f]); \
        __builtin_nontemporal_store(A1, &out_v[(size_t)(N_) * 384 + 128 + f]); \
        __builtin_nontemporal_store(A2, &out_v[(size_t)(N_) * 384 + 256 + f]); \
    }

#define BOUNDARY(GE)                                                           \
    if ((GE) + 1 == end_cur) {                                                 \
        STORE_NODE(cur, acc_s, acc_v0, acc_v1, acc_v2);                        \
        acc_s = acc_v0 = acc_v1 = acc_v2 = 0.f;                                \
        ++cur;                                                                 \
        while (cur < nhi) {                                                    \
            int ne_ = row_ptr[cur + 1];                                        \
            if (ne_ != (GE) + 1) { end_cur = ne_; break; }                     \
            STORE_NODE(cur, 0.f, 0.f, 0.f, 0.f);                               \
            ++cur;                                                             \
        }                                                                      \
    }

__global__ __launch_bounds__(128) void gather_packed_kernel(
    const unsigned short* __restrict__ pv, const unsigned* __restrict__ wrh,
    const float* __restrict__ br, const int* __restrict__ row_ptr,
    const float* __restrict__ e_meta,
    float* __restrict__ out_v, float* __restrict__ out_s)
{
    __shared__ float meta_lds[2][BATCH * 16];

    const int f = threadIdx.x;               // 0..127 feature lane
    const int gid = blockIdx.x;
    const int chunk = (N_NODES_C + GBLOCKS - 1) / GBLOCKS;   // 8
    const int nlo = gid * chunk;
    if (nlo >= N_NODES_C) return;
    const int nhi = min(nlo + chunk, N_NODES_C);

    unsigned wrp0[10], wrp1[10], wrp2[10];
    {
        const unsigned* wp = wrh + (size_t)f * 30;
#pragma unroll
        for (int i = 0; i < 10; ++i) {
            wrp0[i] = wp[i];
            wrp1[i] = wp[10 + i];
            wrp2[i] = wp[20 + i];
        }
#pragma unroll
        for (int i = 0; i < 10; ++i)
            asm volatile("" : "+v"(wrp0[i]), "+v"(wrp1[i]), "+v"(wrp2[i]));
    }
    const float br0 = br[f], br1 = br[128 + f], br2 = br[256 + f];

    const int gbeg = row_ptr[nlo];
    const int gend = row_ptr[nhi];
    const int nedge = gend - gbeg;

    float acc_s = 0.f, acc_v0 = 0.f, acc_v1 = 0.f, acc_v2 = 0.f;

    int cur = nlo;
    while (cur < nhi && row_ptr[cur + 1] == gbeg) {
        STORE_NODE(cur, 0.f, 0.f, 0.f, 0.f);
        ++cur;
    }
    int end_cur = (cur < nhi) ? row_ptr[cur + 1] : gbeg;

    // stage batch 0: 32 records x 64B = 128 f32x4 (one per thread), nt loads
    if (nedge > 0) {
        const f32x4* src0 = (const f32x4*)(e_meta + (size_t)gbeg * 16);
        f32x4 s0 = __builtin_nontemporal_load(src0 + threadIdx.x);
        ((f32x4*)meta_lds[0])[threadIdx.x] = s0;
    }
    __syncthreads();

    const int total_batches = (nedge + BATCH - 1) / BATCH;
    for (int b = 0; b < total_batches; ++b) {
        const int bstart = b * BATCH;
        const int bcount = min(BATCH, nedge - bstart);
        const bool have_next = (b + 1 < total_batches);

        f32x4 st;
        if (have_next) {
            const f32x4* srcn =
                (const f32x4*)(e_meta + (size_t)(gbeg + bstart + BATCH) * 16);
            st = __builtin_nontemporal_load(srcn + threadIdx.x);
        }

        const float* Mb = meta_lds[b & 1];

        u32x3 uA, uB;
        {
            int si = ((const int*)Mb)[14];
            LOADPV(uA, si);
        }

        int t = 0;
        while (t < bcount) {
            if (t + 1 < bcount) {
                int si = ((const int*)(Mb + (t + 1) * 16))[14];
                LOADPV(uB, si);
            }
            COMPUTE_E(Mb + t * 16, uA);
            BOUNDARY(gbeg + bstart + t);
            ++t; if (t >= bcount) break;

            if (t + 1 < bcount) {
                int si = ((const int*)(Mb + (t + 1) * 16))[14];
                LOADPV(uA, si);
            }
            COMPUTE_E(Mb + t * 16, uB);
            BOUNDARY(gbeg + bstart + t);
            ++t;
        }

        if (have_next) ((f32x4*)meta_lds[(b + 1) & 1])[threadIdx.x] = st;
        __syncthreads();
    }
}

// ---------------------------------------------------------------------------
extern "C" void kernel_launch(void* const* d_in, const int* in_sizes, int n_in,
                              void* d_out, int out_size, void* d_ws, size_t ws_size,
                              hipStream_t stream)
{
    const float* s  = (const float*)d_in[0];
    const float* v  = (const float*)d_in[1];
    const float* rp = (const float*)d_in[2];
    const float* W1 = (const float*)d_in[3];
    const float* b1 = (const float*)d_in[4];
    const float* W2 = (const float*)d_in[5];
    const float* b2 = (const float*)d_in[6];
    const float* Wr = (const float*)d_in[7];
    const float* br = (const float*)d_in[8];
    const int* src  = (const int*)d_in[9];
    const int* dst  = (const int*)d_in[10];

    float* out   = (float*)d_out;
    float* out_v = out;                                    // 50000*3*128
    float* out_s = out + (size_t)N_NODES_C * 3 * FDIM;     // 50000*128

    // workspace layout (~105 MB total)
    char* ws = (char*)d_ws;
    float* e_meta = (float*)ws;                 ws += ((size_t)N_EDGES_C * 16 + 256) * sizeof(float);
    unsigned short* W1t = (unsigned short*)ws;  ws += (size_t)128 * 128 * sizeof(unsigned short);
    unsigned short* W2t = (unsigned short*)ws;  ws += (size_t)384 * 128 * sizeof(unsigned short);
    unsigned* wrh = (unsigned*)ws;              ws += (size_t)128 * 30 * sizeof(unsigned);
    int* counts   = (int*)ws;                   ws += (size_t)N_NODES_C * sizeof(int);
    int* row_ptr  = (int*)ws;                   ws += (size_t)(N_NODES_C + 4) * sizeof(int);
    int* row_fill = (int*)ws;                   ws += (size_t)N_NODES_C * sizeof(int);
    int* row_tmp  = (int*)ws;                   ws += (size_t)N_NODES_C * sizeof(int);
    int* partial  = (int*)ws;                   ws += (size_t)256 * sizeof(int);
    int* poffs    = (int*)ws;                   ws += (size_t)256 * sizeof(int);
    unsigned short* h = (unsigned short*)ws;    ws += (size_t)N_NODES_C * 128 * sizeof(unsigned short);
    unsigned short* pv = (unsigned short*)ws;   // 50000 * 1536B = 76.8 MB

    hipMemsetAsync(counts, 0, (size_t)N_NODES_C * sizeof(int), stream);

    k1_kernel<<<K1_VP + K1_CT + K1_PR, 256, 0, stream>>>(
        v, pv, dst, counts, W1, W2, Wr, W1t, W2t, wrh);
    scan1_kernel<<<SC_BLK, 256, 0, stream>>>(counts, row_tmp, partial);
    scan2_kernel<<<1, 256, 0, stream>>>(partial, poffs);
    scan3_kernel<<<SC_BLK, 256, 0, stream>>>(row_tmp, poffs, row_ptr, row_fill);
    k5_kernel<<<K5_ML + K5_FL, 256, 0, stream>>>(
        s, W1t, b1, h, rp, src, dst, row_fill, e_meta);
    mlp2p_kernel<<<dim3(391, 4), 256, 0, stream>>>(h, W2t, b2, pv);

    gather_packed_kernel<<<GBLOCKS, 128, 0, stream>>>(pv, wrh, br, row_ptr,
                                                      e_meta, out_v, out_s);
}

// Round 24
// 185.004 us; speedup vs baseline: 1.0148x; 1.0148x over previous
//
#include <hip/hip_runtime.h>
#include <math.h>

#define N_NODES_C 50000
#define N_EDGES_C 200000
#define FDIM 128
#define NRBF 20
#define CUT 5.0f
#define SC_BLK 196   // ceil(50000/256)
#define GBLOCKS 6250 // 8 nodes per block
#define BATCH 32     // edges staged per LDS batch (32 x 64B = 2KB = 128 float4)

// K1 partition: [vpack 4096 | count 782 | prep_all 272]
#define K1_VP 4096
#define K1_CT 782
#define K1_PR 272
// K5 partition: [mlp1w 782 | fill 782]
#define K5_ML 782
#define K5_FL 782

typedef short  bf16x8 __attribute__((ext_vector_type(8)));
typedef float  f32x4  __attribute__((ext_vector_type(4)));
typedef unsigned int u32x3 __attribute__((ext_vector_type(3)));
typedef _Float16 f16x2 __attribute__((ext_vector_type(2)));

__device__ __forceinline__ unsigned short f32_to_bf16(float f) {
    unsigned u = __float_as_uint(f);
    unsigned r = (u + 0x7FFFu + ((u >> 16) & 1u)) >> 16;   // RNE
    return (unsigned short)r;
}
__device__ __forceinline__ float bf16_to_f32(unsigned short h) {
    return __uint_as_float(((unsigned)h) << 16);
}
__device__ __forceinline__ unsigned short f16_bits(float x) {
    _Float16 h = (_Float16)x;
    unsigned short b;
    __builtin_memcpy(&b, &h, 2);
    return b;
}
__device__ __forceinline__ f16x2 u2h2(unsigned u) {
    f16x2 r;
    __builtin_memcpy(&r, &u, 4);
    return r;
}
__device__ __forceinline__ bf16x8 pack_bf16x8(f32x4 a, f32x4 b) {
    bf16x8 r;
    r[0] = (short)f32_to_bf16(a[0]); r[1] = (short)f32_to_bf16(a[1]);
    r[2] = (short)f32_to_bf16(a[2]); r[3] = (short)f32_to_bf16(a[3]);
    r[4] = (short)f32_to_bf16(b[0]); r[5] = (short)f32_to_bf16(b[1]);
    r[6] = (short)f32_to_bf16(b[2]); r[7] = (short)f32_to_bf16(b[3]);
    return r;
}

// ---------------------------------------------------------------------------
// K1: merged [vpack | count | prep_all] — independent work, block-partitioned.
// ---------------------------------------------------------------------------
__global__ __launch_bounds__(256) void k1_kernel(
    const float* __restrict__ v, unsigned short* __restrict__ pv,
    const int* __restrict__ dst, int* __restrict__ counts,
    const float* __restrict__ W1, const float* __restrict__ W2,
    const float* __restrict__ Wr, unsigned short* __restrict__ W1t,
    unsigned short* __restrict__ W2t, unsigned* __restrict__ wrh)
{
    const int bid = blockIdx.x;
    const int tid = threadIdx.x;

    if (bid < K1_VP) {
        const int total = N_NODES_C * 128;
        for (int idx = bid * 256 + tid; idx < total; idx += K1_VP * 256) {
            int n = idx >> 7, f = idx & 127;
            const float* vr = v + (size_t)n * 384;
            unsigned short v0 = f32_to_bf16(__builtin_nontemporal_load(vr + f));
            unsigned short v1 = f32_to_bf16(__builtin_nontemporal_load(vr + 128 + f));
            unsigned short v2 = f32_to_bf16(__builtin_nontemporal_load(vr + 256 + f));
            char* base = (char*)pv + (size_t)n * 1536 + (size_t)f * 12;
            *(unsigned short*)(base + 6) = v0;
            *(unsigned*)(base + 8) = (unsigned)v1 | ((unsigned)v2 << 16);
        }
    } else if (bid < K1_VP + K1_CT) {
        int e = (bid - K1_VP) * 256 + tid;
        if (e < N_EDGES_C) atomicAdd(counts + dst[e], 1);
    } else {
        int i = (bid - K1_VP - K1_CT) * 256 + tid;
        if (i < 128 * 128) {
            int n = i >> 7, k = i & 127;
            W1t[i] = f32_to_bf16(W1[k * 128 + n]);
        } else if (i < 128 * 128 + 384 * 128) {
            int j = i - 128 * 128;
            int n = j >> 7, k = j & 127;
            W2t[j] = f32_to_bf16(W2[k * 384 + n]);
        } else {
            int idx = i - (128 * 128 + 384 * 128);
            if (idx < 128 * 30) {
                int f  = idx / 30;
                int r  = idx % 30;
                int sec = r / 10, kp = r % 10;
                int col = sec * 128 + f;
                unsigned lo = f16_bits(Wr[(2 * kp)     * 384 + col]);
                unsigned hi = f16_bits(Wr[(2 * kp + 1) * 384 + col]);
                wrh[idx] = lo | (hi << 16);
            }
        }
    }
}

// ---------------------------------------------------------------------------
// CSR scan: 3-kernel parallel scan
// ---------------------------------------------------------------------------
__global__ __launch_bounds__(256) void scan1_kernel(
    const int* __restrict__ counts, int* __restrict__ row_tmp,
    int* __restrict__ partial)
{
    __shared__ int sm[256];
    const int t = threadIdx.x;
    const int idx = blockIdx.x * 256 + t;
    int c = (idx < N_NODES_C) ? counts[idx] : 0;
    int x = c;
    sm[t] = x;
    __syncthreads();
#pragma unroll
    for (int off = 1; off < 256; off <<= 1) {
        int y = (t >= off) ? sm[t - off] : 0;
        __syncthreads();
        x += y;
        sm[t] = x;
        __syncthreads();
    }
    if (idx < N_NODES_C) row_tmp[idx] = x - c;
    if (t == 255) partial[blockIdx.x] = x;
}

__global__ __launch_bounds__(256) void scan2_kernel(
    const int* __restrict__ partial, int* __restrict__ poffs)
{
    __shared__ int sm[256];
    const int t = threadIdx.x;
    int c = (t < SC_BLK) ? partial[t] : 0;
    int x = c;
    sm[t] = x;
    __syncthreads();
#pragma unroll
    for (int off = 1; off < 256; off <<= 1) {
        int y = (t >= off) ? sm[t - off] : 0;
        __syncthreads();
        x += y;
        sm[t] = x;
        __syncthreads();
    }
    if (t < SC_BLK) poffs[t] = x - c;
}

__global__ __launch_bounds__(256) void scan3_kernel(
    const int* __restrict__ row_tmp, const int* __restrict__ poffs,
    int* __restrict__ row_ptr, int* __restrict__ row_fill)
{
    const int idx = blockIdx.x * 256 + threadIdx.x;
    if (idx < N_NODES_C) {
        int rp = row_tmp[idx] + poffs[blockIdx.x];
        row_ptr[idx]  = rp;
        row_fill[idx] = rp;
    }
    if (idx == 0) row_ptr[N_NODES_C] = N_EDGES_C;
}

// ---------------------------------------------------------------------------
// K5: merged [mlp1w | fill]
// ---------------------------------------------------------------------------
__global__ __launch_bounds__(256) void k5_kernel(
    const float* __restrict__ s, const unsigned short* __restrict__ W1t,
    const float* __restrict__ b1, unsigned short* __restrict__ h,
    const float* __restrict__ rel_pos, const int* __restrict__ src,
    const int* __restrict__ dst, int* __restrict__ row_fill,
    float* __restrict__ e_meta)
{
    __shared__ unsigned short w1lds[128 * 136];   // 34.8 KB (mlp1w branch)

    const int bid = blockIdx.x;
    const int tid = threadIdx.x;

    if (bid < K5_ML) {
#pragma unroll
        for (int j = 0; j < 8; ++j) {
            int fi = tid + j * 256;
            int row  = fi >> 4;
            int colq = fi & 15;
            *(float4*)&w1lds[row * 136 + colq * 8] =
                *(const float4*)(W1t + (size_t)fi * 8);
        }
        __syncthreads();

        const int wv = tid >> 6, lane = tid & 63;
        const int m0 = bid * 64 + wv * 16;
        const int lr = lane & 15, lg = lane >> 4;
        int arow = m0 + lr; if (arow >= N_NODES_C) arow = N_NODES_C - 1;

        f32x4 acc[8];
#pragma unroll
        for (int nt = 0; nt < 8; ++nt) acc[nt] = (f32x4){0.f, 0.f, 0.f, 0.f};

#pragma unroll
        for (int kt = 0; kt < 4; ++kt) {
            const int k0 = kt * 32 + lg * 8;
            const f32x4* ap = (const f32x4*)(s + (size_t)arow * 128 + k0);
            f32x4 a0 = __builtin_nontemporal_load(ap);
            f32x4 a1 = __builtin_nontemporal_load(ap + 1);
            bf16x8 af = pack_bf16x8(a0, a1);
#pragma unroll
            for (int nt = 0; nt < 8; ++nt) {
                bf16x8 bf = *(const bf16x8*)&w1lds[(nt * 16 + lr) * 136 + k0];
                acc[nt] = __builtin_amdgcn_mfma_f32_16x16x32_bf16(af, bf, acc[nt], 0, 0, 0);
            }
        }

        const int crow = m0 + lg * 4;
#pragma unroll
        for (int nt = 0; nt < 8; ++nt) {
            int col = nt * 16 + lr;
            float bb = b1[col];
#pragma unroll
            for (int r = 0; r < 4; ++r) {
                int m = crow + r;
                if (m < N_NODES_C) {
                    float x = acc[nt][r] + bb;
                    x = x / (1.f + __expf(-x));
                    h[(size_t)m * 128 + col] = f32_to_bf16(x);
                }
            }
        }
    } else {
        int e = (bid - K5_ML) * 256 + tid;
        if (e >= N_EDGES_C) return;

        int pos = atomicAdd(row_fill + dst[e], 1);

        float x = rel_pos[3 * e + 0];
        float y = rel_pos[3 * e + 1];
        float z = rel_pos[3 * e + 2];
        float d = sqrtf(x * x + y * y + z * z);
        float invd = 1.0f / d;

        float s1 = 0.f, c1 = 0.f, fcut = 0.f, amp = 0.f;
        if (d < CUT) {
            sincosf((3.14159265358979f / CUT) * d, &s1, &c1);
            fcut = 0.5f * (c1 + 1.0f);
            amp  = invd * fcut;
        }

        float rb[NRBF];
        float sk = s1, ck = c1;
#pragma unroll
        for (int k = 0; k < NRBF; ++k) {
            rb[k] = sk * amp;
            float sn = sk * c1 + ck * s1;
            ck = ck * c1 - sk * s1;
            sk = sn;
        }

        unsigned pk[10];
#pragma unroll
        for (int kp = 0; kp < 10; ++kp)
            pk[kp] = (unsigned)f16_bits(rb[2 * kp]) | ((unsigned)f16_bits(rb[2 * kp + 1]) << 16);

        float4* mp = (float4*)(e_meta + (size_t)pos * 16);
        mp[0] = make_float4(x * invd, y * invd, z * invd, fcut);
        mp[1] = make_float4(__uint_as_float(pk[0]), __uint_as_float(pk[1]),
                            __uint_as_float(pk[2]), __uint_as_float(pk[3]));
        mp[2] = make_float4(__uint_as_float(pk[4]), __uint_as_float(pk[5]),
                            __uint_as_float(pk[6]), __uint_as_float(pk[7]));
        mp[3] = make_float4(__uint_as_float(pk[8]), __uint_as_float(pk[9]),
                            __int_as_float(src[e]), 0.f);
    }
}

// ---------------------------------------------------------------------------
// MLP stage 2 -> p-half of pv (bytes 0..5): EXACT round-22 version (the
// round-23 per-t-grid restructure was neutral-negative; reverted).
// ---------------------------------------------------------------------------
__global__ __launch_bounds__(256) void mlp2p_kernel(
    const unsigned short* __restrict__ h, const unsigned short* __restrict__ W2t,
    const float* __restrict__ b2, unsigned short* __restrict__ pv)
{
    __shared__ unsigned short wlds[2][3 * 16 * 136];   // [half] 26.1 KB

    const int tid = threadIdx.x;
    const int wv = tid >> 6, lane = tid & 63;
    const int rg = wv & 1;            // row-group
    const int hf = wv >> 1;           // nt-half
    const int m0 = blockIdx.x * 32 + rg * 16;
    const int lr = lane & 15, lg = lane >> 4;
    int arow = m0 + lr; if (arow >= N_NODES_C) arow = N_NODES_C - 1;

    bf16x8 af2[4];
#pragma unroll
    for (int kt = 0; kt < 4; ++kt)
        af2[kt] = *(const bf16x8*)(h + (size_t)arow * 128 + kt * 32 + lg * 8);

    const int crow = m0 + lg * 4;

    for (int t = 0; t < 4; ++t) {
        __syncthreads();
#pragma unroll
        for (int j = 0; j < 6; ++j) {
            int fi = tid + j * 256;            // 0..1535
            int half = (fi >= 768) ? 1 : 0;
            int rem  = fi - half * 768;
            int c    = rem >> 8;               // 0..2
            int r2   = rem & 255;
            int row  = r2 >> 4;
            int colq = r2 & 15;
            int nt   = half * 4 + t;
            *(float4*)&wlds[half][(c * 16 + row) * 136 + colq * 8] =
                *(const float4*)(W2t +
                    ((size_t)(c * 128 + nt * 16 + row) * 128 + colq * 8));
        }
        __syncthreads();

        const unsigned short* W = wlds[hf];
        f32x4 a0 = (f32x4){0.f, 0.f, 0.f, 0.f};
        f32x4 a1 = (f32x4){0.f, 0.f, 0.f, 0.f};
        f32x4 a2 = (f32x4){0.f, 0.f, 0.f, 0.f};
#pragma unroll
        for (int kt = 0; kt < 4; ++kt) {
            const int k0 = kt * 32 + lg * 8;
            bf16x8 bf0 = *(const bf16x8*)&W[(      lr) * 136 + k0];
            bf16x8 bf1 = *(const bf16x8*)&W[(16 +  lr) * 136 + k0];
            bf16x8 bf2 = *(const bf16x8*)&W[(32 +  lr) * 136 + k0];
            a0 = __builtin_amdgcn_mfma_f32_16x16x32_bf16(af2[kt], bf0, a0, 0, 0, 0);
            a1 = __builtin_amdgcn_mfma_f32_16x16x32_bf16(af2[kt], bf1, a1, 0, 0, 0);
            a2 = __builtin_amdgcn_mfma_f32_16x16x32_bf16(af2[kt], bf2, a2, 0, 0, 0);
        }

        const int col = (hf * 4 + t) * 16 + lr;
        const float bb0 = b2[col], bb1 = b2[128 + col], bb2 = b2[256 + col];
#pragma unroll
        for (int r = 0; r < 4; ++r) {
            int m = crow + r;
            if (m < N_NODES_C) {
                unsigned p0 = f32_to_bf16(a0[r] + bb0);
                unsigned p1 = f32_to_bf16(a1[r] + bb1);
                unsigned short p2 = f32_to_bf16(a2[r] + bb2);
                char* base = (char*)pv + (size_t)m * 1536 + (size_t)col * 12;
                *(unsigned*)(base) = p0 | (p1 << 16);
                *(unsigned short*)(base + 4) = p2;
            }
        }
    }
}

// ---------------------------------------------------------------------------
// Gather: round-15 structure + DEPTH-4 pv prefetch (round-24: depth-2 covers
// only ~100cy of the ~300-900cy pv load latency — the measured 44% HBM +
// 46% VALU + 46% occ signature is under-covered latency; 3 loads in flight
// triples the cover at +9 VGPR).
// ---------------------------------------------------------------------------
#define COMPUTE_E(M_, U)                                                       \
    {                                                                          \
        const float4 m0 = *(const float4*)(M_);                                \
        const unsigned* mu_ = (const unsigned*)((M_) + 4);                     \
        float w0 = m0.w * br0, w1 = m0.w * br1, w2 = m0.w * br2;               \
        _Pragma("unroll")                                                      \
        for (int kp = 0; kp < 10; ++kp) {                                      \
            f16x2 rh = u2h2(mu_[kp]);                                          \
            w0 = __builtin_amdgcn_fdot2(rh, u2h2(wrp0[kp]), w0, false);        \
            w1 = __builtin_amdgcn_fdot2(rh, u2h2(wrp1[kp]), w1, false);        \
            w2 = __builtin_amdgcn_fdot2(rh, u2h2(wrp2[kp]), w2, false);        \
        }                                                                      \
        float P0 = bf16_to_f32((unsigned short)((U).x & 0xFFFFu));             \
        float P1 = bf16_to_f32((unsigned short)((U).x >> 16));                 \
        float P2 = bf16_to_f32((unsigned short)((U).y & 0xFFFFu));             \
        float V0 = bf16_to_f32((unsigned short)((U).y >> 16));                 \
        float V1 = bf16_to_f32((unsigned short)((U).z & 0xFFFFu));             \
        float V2 = bf16_to_f32((unsigned short)((U).z >> 16));                 \
        float sv = w0 * P0;                                                    \
        float ss = w1 * P1;                                                    \
        float sr = w2 * P2;                                                    \
        acc_s  += ss;                                                          \
        acc_v0 += V0 * sv + m0.x * sr;                                         \
        acc_v1 += V1 * sv + m0.y * sr;                                         \
        acc_v2 += V2 * sv + m0.z * sr;                                         \
    }

#define LOADPV(U, SI)                                                          \
    U = *(const u32x3*)((const char*)pv + (size_t)(SI) * 1536 + (size_t)f * 12);

#define PREFETCH(SLOT, TT)                                                     \
    if ((TT) < bcount) {                                                       \
        int si_ = ((const int*)(Mb + (TT) * 16))[14];                          \
        LOADPV(SLOT, si_);                                                     \
    }

#define STORE_NODE(N_, AS, A0, A1, A2)                                         \
    {                                                                          \
        __builtin_nontemporal_store(AS, &out_s[(size_t)(N_) * 128 + f]);       \
        __builtin_nontemporal_store(A0, &out_v[(size_t)(N_) * 384 +       f]); \
        __builtin_nontemporal_store(A1, &out_v[(size_t)(N_) * 384 + 128 + f]); \
        __builtin_nontemporal_store(A2, &out_v[(size_t)(N_) * 384 + 256 + f]); \
    }

#define BOUNDARY(GE)                                                           \
    if ((GE) + 1 == end_cur) {                                                 \
        STORE_NODE(cur, acc_s, acc_v0, acc_v1, acc_v2);                        \
        acc_s = acc_v0 = acc_v1 = acc_v2 = 0.f;                                \
        ++cur;                                                                 \
        while (cur < nhi) {                                                    \
            int ne_ = row_ptr[cur + 1];                                        \
            if (ne_ != (GE) + 1) { end_cur = ne_; break; }                     \
            STORE_NODE(cur, 0.f, 0.f, 0.f, 0.f);                               \
            ++cur;                                                             \
        }                                                                      \
    }

__global__ __launch_bounds__(128) void gather_packed_kernel(
    const unsigned short* __restrict__ pv, const unsigned* __restrict__ wrh,
    const float* __restrict__ br, const int* __restrict__ row_ptr,
    const float* __restrict__ e_meta,
    float* __restrict__ out_v, float* __restrict__ out_s)
{
    __shared__ float meta_lds[2][BATCH * 16];

    const int f = threadIdx.x;               // 0..127 feature lane
    const int gid = blockIdx.x;
    const int chunk = (N_NODES_C + GBLOCKS - 1) / GBLOCKS;   // 8
    const int nlo = gid * chunk;
    if (nlo >= N_NODES_C) return;
    const int nhi = min(nlo + chunk, N_NODES_C);

    unsigned wrp0[10], wrp1[10], wrp2[10];
    {
        const unsigned* wp = wrh + (size_t)f * 30;
#pragma unroll
        for (int i = 0; i < 10; ++i) {
            wrp0[i] = wp[i];
            wrp1[i] = wp[10 + i];
            wrp2[i] = wp[20 + i];
        }
#pragma unroll
        for (int i = 0; i < 10; ++i)
            asm volatile("" : "+v"(wrp0[i]), "+v"(wrp1[i]), "+v"(wrp2[i]));
    }
    const float br0 = br[f], br1 = br[128 + f], br2 = br[256 + f];

    const int gbeg = row_ptr[nlo];
    const int gend = row_ptr[nhi];
    const int nedge = gend - gbeg;

    float acc_s = 0.f, acc_v0 = 0.f, acc_v1 = 0.f, acc_v2 = 0.f;

    int cur = nlo;
    while (cur < nhi && row_ptr[cur + 1] == gbeg) {
        STORE_NODE(cur, 0.f, 0.f, 0.f, 0.f);
        ++cur;
    }
    int end_cur = (cur < nhi) ? row_ptr[cur + 1] : gbeg;

    // stage batch 0: 32 records x 64B = 128 f32x4 (one per thread), nt loads
    if (nedge > 0) {
        const f32x4* src0 = (const f32x4*)(e_meta + (size_t)gbeg * 16);
        f32x4 s0 = __builtin_nontemporal_load(src0 + threadIdx.x);
        ((f32x4*)meta_lds[0])[threadIdx.x] = s0;
    }
    __syncthreads();

    const int total_batches = (nedge + BATCH - 1) / BATCH;
    for (int b = 0; b < total_batches; ++b) {
        const int bstart = b * BATCH;
        const int bcount = min(BATCH, nedge - bstart);
        const bool have_next = (b + 1 < total_batches);

        f32x4 st;
        if (have_next) {
            const f32x4* srcn =
                (const f32x4*)(e_meta + (size_t)(gbeg + bstart + BATCH) * 16);
            st = __builtin_nontemporal_load(srcn + threadIdx.x);
        }

        const float* Mb = meta_lds[b & 1];

        u32x3 u0, u1, u2, u3;
        PREFETCH(u0, 0)
        PREFETCH(u1, 1)
        PREFETCH(u2, 2)

        int t = 0;
        while (t < bcount) {
            PREFETCH(u3, t + 3)
            COMPUTE_E(Mb + t * 16, u0);
            BOUNDARY(gbeg + bstart + t);
            ++t; if (t >= bcount) break;

            PREFETCH(u0, t + 3)
            COMPUTE_E(Mb + t * 16, u1);
            BOUNDARY(gbeg + bstart + t);
            ++t; if (t >= bcount) break;

            PREFETCH(u1, t + 3)
            COMPUTE_E(Mb + t * 16, u2);
            BOUNDARY(gbeg + bstart + t);
            ++t; if (t >= bcount) break;

            PREFETCH(u2, t + 3)
            COMPUTE_E(Mb + t * 16, u3);
            BOUNDARY(gbeg + bstart + t);
            ++t;
        }

        if (have_next) ((f32x4*)meta_lds[(b + 1) & 1])[threadIdx.x] = st;
        __syncthreads();
    }
}

// ---------------------------------------------------------------------------
extern "C" void kernel_launch(void* const* d_in, const int* in_sizes, int n_in,
                              void* d_out, int out_size, void* d_ws, size_t ws_size,
                              hipStream_t stream)
{
    const float* s  = (const float*)d_in[0];
    const float* v  = (const float*)d_in[1];
    const float* rp = (const float*)d_in[2];
    const float* W1 = (const float*)d_in[3];
    const float* b1 = (const float*)d_in[4];
    const float* W2 = (const float*)d_in[5];
    const float* b2 = (const float*)d_in[6];
    const float* Wr = (const float*)d_in[7];
    const float* br = (const float*)d_in[8];
    const int* src  = (const int*)d_in[9];
    const int* dst  = (const int*)d_in[10];

    float* out   = (float*)d_out;
    float* out_v = out;                                    // 50000*3*128
    float* out_s = out + (size_t)N_NODES_C * 3 * FDIM;     // 50000*128

    // workspace layout (~105 MB total)
    char* ws = (char*)d_ws;
    float* e_meta = (float*)ws;                 ws += ((size_t)N_EDGES_C * 16 + 256) * sizeof(float);
    unsigned short* W1t = (unsigned short*)ws;  ws += (size_t)128 * 128 * sizeof(unsigned short);
    unsigned short* W2t = (unsigned short*)ws;  ws += (size_t)384 * 128 * sizeof(unsigned short);
    unsigned* wrh = (unsigned*)ws;              ws += (size_t)128 * 30 * sizeof(unsigned);
    int* counts   = (int*)ws;                   ws += (size_t)N_NODES_C * sizeof(int);
    int* row_ptr  = (int*)ws;                   ws += (size_t)(N_NODES_C + 4) * sizeof(int);
    int* row_fill = (int*)ws;                   ws += (size_t)N_NODES_C * sizeof(int);
    int* row_tmp  = (int*)ws;                   ws += (size_t)N_NODES_C * sizeof(int);
    int* partial  = (int*)ws;                   ws += (size_t)256 * sizeof(int);
    int* poffs    = (int*)ws;                   ws += (size_t)256 * sizeof(int);
    unsigned short* h = (unsigned short*)ws;    ws += (size_t)N_NODES_C * 128 * sizeof(unsigned short);
    unsigned short* pv = (unsigned short*)ws;   // 50000 * 1536B = 76.8 MB

    hipMemsetAsync(counts, 0, (size_t)N_NODES_C * sizeof(int), stream);

    k1_kernel<<<K1_VP + K1_CT + K1_PR, 256, 0, stream>>>(
        v, pv, dst, counts, W1, W2, Wr, W1t, W2t, wrh);
    scan1_kernel<<<SC_BLK, 256, 0, stream>>>(counts, row_tmp, partial);
    scan2_kernel<<<1, 256, 0, stream>>>(partial, poffs);
    scan3_kernel<<<SC_BLK, 256, 0, stream>>>(row_tmp, poffs, row_ptr, row_fill);
    k5_kernel<<<K5_ML + K5_FL, 256, 0, stream>>>(
        s, W1t, b1, h, rp, src, dst, row_fill, e_meta);
    mlp2p_kernel<<<(N_NODES_C + 31) / 32, 256, 0, stream>>>(h, W2t, b2, pv);

    gather_packed_kernel<<<GBLOCKS, 128, 0, stream>>>(pv, wrh, br, row_ptr,
                                                      e_meta, out_v, out_s);
}